// Round 2
// baseline (2290.228 us; speedup 1.0000x reference)
//
#include <hip/hip_runtime.h>
#include <math.h>

#define CC 256       // channels = HEADS * HD
#define HEADS 4
#define HD 64
#define NG 64        // num graphs
#define SCAN_BS 512

// ---------------- CSR build (by dst) ----------------
__global__ void hist_kernel(const int* __restrict__ dst, int* __restrict__ deg, int E) {
  int e = blockIdx.x * blockDim.x + threadIdx.x;
  if (e < E) atomicAdd(&deg[dst[e]], 1);
}

__global__ void scan1_kernel(const int* __restrict__ deg, int* __restrict__ exc,
                             int* __restrict__ partial, int n) {
  __shared__ int s[SCAN_BS];
  int t = threadIdx.x;
  int g = blockIdx.x * SCAN_BS + t;
  int v = (g < n) ? deg[g] : 0;
  s[t] = v;
  __syncthreads();
  for (int off = 1; off < SCAN_BS; off <<= 1) {
    int add = (t >= off) ? s[t - off] : 0;
    __syncthreads();
    s[t] += add;
    __syncthreads();
  }
  if (g < n) exc[g] = s[t] - v;              // exclusive within chunk
  if (t == SCAN_BS - 1) partial[blockIdx.x] = s[t];
}

__global__ void scan2_kernel(int* __restrict__ partial, int nb) {
  __shared__ int s[SCAN_BS];
  int t = threadIdx.x;
  int v = (t < nb) ? partial[t] : 0;
  s[t] = v;
  __syncthreads();
  for (int off = 1; off < SCAN_BS; off <<= 1) {
    int add = (t >= off) ? s[t - off] : 0;
    __syncthreads();
    s[t] += add;
    __syncthreads();
  }
  if (t < nb) partial[t] = s[t] - v;         // exclusive chunk offsets
}

__global__ void scan3_kernel(const int* __restrict__ exc, const int* __restrict__ partial,
                             int* __restrict__ row_start, int* __restrict__ cursor,
                             int n, int E) {
  int g = blockIdx.x * blockDim.x + threadIdx.x;
  if (g < n) {
    int v = exc[g] + partial[g / SCAN_BS];
    row_start[g] = v;
    cursor[g] = v;
  }
  if (g == n) row_start[n] = E;
}

__global__ void scatter_kernel(const int* __restrict__ srcArr, const int* __restrict__ dstArr,
                               int* __restrict__ cursor, int* __restrict__ csr_src,
                               int* __restrict__ csr_dst, int E) {
  int e = blockIdx.x * blockDim.x + threadIdx.x;
  if (e < E) {
    int d = dstArr[e];
    int p = atomicAdd(&cursor[d], 1);
    csr_src[p] = srcArr[e];
    csr_dst[p] = d;
  }
}

// ---------------- fp32 SGEMM: C = A(MxK) @ B(KxN) + bias, K=N=256 ----------------
__global__ __launch_bounds__(256) void sgemm_bias(const float* __restrict__ A,
                                                  const float* __restrict__ B,
                                                  const float* __restrict__ bias,
                                                  float* __restrict__ Cout, int M) {
  __shared__ float As[8][128];
  __shared__ float Bs[8][128];
  const int K = 256, N = 256;
  int t = threadIdx.x;
  int tx = t & 15, ty = t >> 4;
  int bm = blockIdx.x, bn = blockIdx.y;

  float acc[8][8];
#pragma unroll
  for (int i = 0; i < 8; ++i)
#pragma unroll
    for (int j = 0; j < 8; ++j) acc[i][j] = 0.f;

  int arow = t >> 1;            // 0..127
  int akq = (t & 1) * 4;        // 0 or 4
  int brow = t >> 5;            // 0..7
  int bcol = (t & 31) * 4;      // 0..124
  int arow_g = bm * 128 + arow;

  for (int kt = 0; kt < K; kt += 8) {
    float4 a = make_float4(0.f, 0.f, 0.f, 0.f);
    if (arow_g < M) a = *(const float4*)(A + (size_t)arow_g * K + kt + akq);
    float4 b = *(const float4*)(B + (size_t)(kt + brow) * N + bn * 128 + bcol);
    __syncthreads();
    As[akq + 0][arow] = a.x;
    As[akq + 1][arow] = a.y;
    As[akq + 2][arow] = a.z;
    As[akq + 3][arow] = a.w;
    *(float4*)&Bs[brow][bcol] = b;
    __syncthreads();
#pragma unroll
    for (int kk = 0; kk < 8; ++kk) {
      float4 a0 = *(const float4*)&As[kk][ty * 4];
      float4 a1 = *(const float4*)&As[kk][ty * 4 + 64];
      float4 b0 = *(const float4*)&Bs[kk][tx * 4];
      float4 b1 = *(const float4*)&Bs[kk][tx * 4 + 64];
      float av[8] = {a0.x, a0.y, a0.z, a0.w, a1.x, a1.y, a1.z, a1.w};
      float bw[8] = {b0.x, b0.y, b0.z, b0.w, b1.x, b1.y, b1.z, b1.w};
#pragma unroll
      for (int i = 0; i < 8; ++i)
#pragma unroll
        for (int j = 0; j < 8; ++j) acc[i][j] = fmaf(av[i], bw[j], acc[i][j]);
    }
  }

  int c0 = bn * 128 + tx * 4;
  float4 bb0 = *(const float4*)(bias + c0);
  float4 bb1 = *(const float4*)(bias + c0 + 64);
  float bbv[8] = {bb0.x, bb0.y, bb0.z, bb0.w, bb1.x, bb1.y, bb1.z, bb1.w};
#pragma unroll
  for (int i = 0; i < 8; ++i) {
    int r = bm * 128 + ((i < 4) ? (ty * 4 + i) : (64 + ty * 4 + (i - 4)));
    if (r >= M) continue;
    float4 o0 = make_float4(acc[i][0] + bbv[0], acc[i][1] + bbv[1],
                            acc[i][2] + bbv[2], acc[i][3] + bbv[3]);
    float4 o1 = make_float4(acc[i][4] + bbv[4], acc[i][5] + bbv[5],
                            acc[i][6] + bbv[6], acc[i][7] + bbv[7]);
    *(float4*)(Cout + (size_t)r * N + c0) = o0;
    *(float4*)(Cout + (size_t)r * N + c0 + 64) = o1;
  }
}

// ---------------- attention phase 1: per-edge logits ----------------
// wave per edge: lane covers (head = lane>>4, 4 dims at (lane&15)*4).
// Q row read by dst (CSR order -> dst sorted -> high L1/L2 reuse), K row gathered.
__global__ __launch_bounds__(256) void edge_logits_kernel(const float* __restrict__ Q,
                                                          const float* __restrict__ K,
                                                          const int* __restrict__ csr_src,
                                                          const int* __restrict__ csr_dst,
                                                          float* __restrict__ logits, int E) {
  int wave = threadIdx.x >> 6;
  int lane = threadIdx.x & 63;
  int e = blockIdx.x * 4 + wave;
  if (e >= E) return;
  int s = csr_src[e];
  int d = csr_dst[e];
  // lane*4 = (lane>>4)*64 + (lane&15)*4 : contiguous 1 KB row read
  const float4 qv = *(const float4*)(Q + (size_t)d * CC + lane * 4);
  const float4 kv = *(const float4*)(K + (size_t)s * CC + lane * 4);
  float dot = qv.x * kv.x + qv.y * kv.y + qv.z * kv.z + qv.w * kv.w;
#pragma unroll
  for (int off = 1; off < 16; off <<= 1) dot += __shfl_xor(dot, off, 64);
  if ((lane & 15) == 0) {
    int h = lane >> 4;
    logits[(size_t)h * E + e] = dot * 0.125f;   // 1/sqrt(64)
  }
}

// ---------------- attention phase 2: segment softmax over CSR rows ----------------
// thread = (head, node); grid covers H*N. In-place logits -> normalized weights.
__global__ void seg_softmax_kernel(float* __restrict__ w, const int* __restrict__ row_start,
                                   int N, int E) {
  int t = blockIdx.x * blockDim.x + threadIdx.x;
  if (t >= HEADS * N) return;
  int h = t / N;
  int n = t - h * N;
  float* plane = w + (size_t)h * E;
  int s0 = row_start[n], s1 = row_start[n + 1];
  if (s0 >= s1) return;
  float m = -1e30f, z = 0.f;
  for (int i = s0; i < s1; ++i) {
    float l = plane[i];
    float mn = fmaxf(m, l);
    z = z * expf(m - mn) + expf(l - mn);
    m = mn;
  }
  float rz = 1.f / z;
  for (int i = s0; i < s1; ++i) plane[i] = expf(plane[i] - m) * rz;
}

// ---------------- attention phase 3: weighted V aggregation ----------------
// block = node, wave = head, lane = dim
__global__ __launch_bounds__(256) void aggregate_kernel(const float* __restrict__ V,
                                                        const float* __restrict__ w,
                                                        const int* __restrict__ row_start,
                                                        const int* __restrict__ csr_src,
                                                        float* __restrict__ hout, int E) {
  int node = blockIdx.x;
  int wave = threadIdx.x >> 6;
  int s0 = row_start[node], s1 = row_start[node + 1];
  const float* wplane = w + (size_t)wave * E;
  float acc = 0.f;
  for (int i = s0; i < s1; ++i) {
    int s = csr_src[i];
    float wt = wplane[i];
    acc = fmaf(wt, V[(size_t)s * CC + threadIdx.x], acc);
  }
  hout[(size_t)node * CC + threadIdx.x] = fmaxf(acc, 0.f);
}

// ---------------- graph boundaries from sorted batch ----------------
__global__ void gbounds_kernel(const int* __restrict__ batch, int* __restrict__ gstart,
                               int N, int G) {
  int n = blockIdx.x * blockDim.x + threadIdx.x;
  if (n >= N) return;
  int b = batch[n];
  if (n == 0) {
    for (int g = 0; g <= b; ++g) gstart[g] = 0;
  } else {
    int pb = batch[n - 1];
    if (pb != b)
      for (int g = pb + 1; g <= b; ++g) gstart[g] = n;
  }
  if (n == N - 1) {
    for (int g = b + 1; g <= G; ++g) gstart[g] = N;
  }
}

// ---------------- pool: one block per graph, thread = channel ----------------
__global__ void pool_kernel(const float* __restrict__ h, const int* __restrict__ gstart,
                            float* __restrict__ gpool) {
  int g = blockIdx.x, c = threadIdx.x;
  int s = gstart[g], e = gstart[g + 1];
  float acc = 0.f;
  for (int n = s; n < e; ++n) acc += h[(size_t)n * CC + c];
  gpool[g * CC + c] = acc;
}

// ---------------- MLP head: relu(g@W1+b1)@W2+b2 ----------------
__global__ void head_kernel(const float* __restrict__ gpool, const float* __restrict__ W1,
                            const float* __restrict__ b1, const float* __restrict__ W2,
                            const float* __restrict__ b2, float* __restrict__ out) {
  __shared__ float hid[64];
  int g = blockIdx.x, t = threadIdx.x;
  float acc = b1[t];
  for (int i = 0; i < CC; ++i) acc = fmaf(gpool[g * CC + i], W1[i * 64 + t], acc);
  hid[t] = fmaxf(acc, 0.f);
  __syncthreads();
  if (t < 16) {
    float o = b2[t];
    for (int i = 0; i < 64; ++i) o = fmaf(hid[i], W2[i * 16 + t], o);
    out[g * 16 + t] = o;
  }
}

extern "C" void kernel_launch(void* const* d_in, const int* in_sizes, int n_in,
                              void* d_out, int out_size, void* d_ws, size_t ws_size,
                              hipStream_t stream) {
  const float* x  = (const float*)d_in[0];
  const int* ei   = (const int*)d_in[1];
  const int* batch = (const int*)d_in[2];
  const float* Wq = (const float*)d_in[3];
  const float* bq = (const float*)d_in[4];
  const float* Wk = (const float*)d_in[5];
  const float* bk = (const float*)d_in[6];
  const float* Wv = (const float*)d_in[7];
  const float* bv = (const float*)d_in[8];
  const float* W1 = (const float*)d_in[9];
  const float* b1 = (const float*)d_in[10];
  const float* W2 = (const float*)d_in[11];
  const float* b2 = (const float*)d_in[12];
  float* out = (float*)d_out;

  int N = in_sizes[0] / CC;
  int E = in_sizes[1] / 2;
  int L = in_sizes[3] / (CC * CC);
  const int* src = ei;
  const int* dst = ei + E;

  size_t off = 0;
  auto alloc = [&](size_t bytes) -> void* {
    void* p = (char*)d_ws + off;
    off += (bytes + 255) & ~(size_t)255;
    return p;
  };
  float* hbuf = (float*)alloc((size_t)N * CC * 4);
  float* Qb = (float*)alloc((size_t)N * CC * 4);
  float* Kb = (float*)alloc((size_t)N * CC * 4);
  float* Vb = (float*)alloc((size_t)N * CC * 4);
  int* deg = (int*)alloc((size_t)N * 4);
  int* exc = (int*)alloc((size_t)N * 4);
  int* partial = (int*)alloc(SCAN_BS * 4);
  int* row_start = (int*)alloc((size_t)(N + 1) * 4);
  int* cursor = (int*)alloc((size_t)N * 4);
  int* csr_src = (int*)alloc((size_t)E * 4);
  int* csr_dst = (int*)alloc((size_t)E * 4);
  float* wbuf = (float*)alloc((size_t)E * HEADS * 4);
  int* gstart = (int*)alloc((NG + 1) * 4);
  float* gpool = (float*)alloc((size_t)NG * CC * 4);

  // CSR by dst
  hipMemsetAsync(deg, 0, (size_t)N * 4, stream);
  int eb = (E + 255) / 256;
  hist_kernel<<<eb, 256, 0, stream>>>(dst, deg, E);
  int nb = (N + SCAN_BS - 1) / SCAN_BS;
  scan1_kernel<<<nb, SCAN_BS, 0, stream>>>(deg, exc, partial, N);
  scan2_kernel<<<1, SCAN_BS, 0, stream>>>(partial, nb);
  scan3_kernel<<<(N + 1 + 255) / 256, 256, 0, stream>>>(exc, partial, row_start, cursor, N, E);
  scatter_kernel<<<eb, 256, 0, stream>>>(src, dst, cursor, csr_src, csr_dst, E);

  // layers
  dim3 gemmGrid((N + 127) / 128, CC / 128);
  int ewb = (E + 3) / 4;                       // wave-per-edge blocks
  int smb = (HEADS * N + 255) / 256;
  for (int l = 0; l < L; ++l) {
    const float* hin = (l == 0) ? x : hbuf;
    sgemm_bias<<<gemmGrid, 256, 0, stream>>>(hin, Wq + (size_t)l * CC * CC, bq + l * CC, Qb, N);
    sgemm_bias<<<gemmGrid, 256, 0, stream>>>(hin, Wk + (size_t)l * CC * CC, bk + l * CC, Kb, N);
    sgemm_bias<<<gemmGrid, 256, 0, stream>>>(hin, Wv + (size_t)l * CC * CC, bv + l * CC, Vb, N);
    edge_logits_kernel<<<ewb, 256, 0, stream>>>(Qb, Kb, csr_src, csr_dst, wbuf, E);
    seg_softmax_kernel<<<smb, 256, 0, stream>>>(wbuf, row_start, N, E);
    aggregate_kernel<<<N, 256, 0, stream>>>(Vb, wbuf, row_start, csr_src, hbuf, E);
  }

  // pool + head
  gbounds_kernel<<<(N + 255) / 256, 256, 0, stream>>>(batch, gstart, N, NG);
  pool_kernel<<<NG, CC, 0, stream>>>(hbuf, gstart, gpool);
  head_kernel<<<NG, 64, 0, stream>>>(gpool, W1, b1, W2, b2, out);
}

// Round 4
// 1621.031 us; speedup vs baseline: 1.4128x; 1.4128x over previous
//
#include <hip/hip_runtime.h>
#include <math.h>

#define CC 256       // channels = HEADS * HD
#define HEADS 4
#define HD 64
#define NG 64        // num graphs
#define SCAN_BS 512
#define QKVS 768     // fused QKV row stride
#define LDK 40       // padded LDS k-stride (bf16 elems): breaks bank periodicity, keeps 16B align

typedef __attribute__((ext_vector_type(8))) short s16x8;   // 8 x bf16 (4 VGPRs) per guide §3
typedef __attribute__((ext_vector_type(4))) float f32x4;

static __device__ __forceinline__ float bf2f(unsigned short u) {
  return (float)__builtin_bit_cast(__bf16, u);
}

// ---------------- CSR build (by dst) ----------------
__global__ void hist_kernel(const int* __restrict__ dst, int* __restrict__ deg, int E) {
  int e = blockIdx.x * blockDim.x + threadIdx.x;
  if (e < E) atomicAdd(&deg[dst[e]], 1);
}

__global__ void scan1_kernel(const int* __restrict__ deg, int* __restrict__ exc,
                             int* __restrict__ partial, int n) {
  __shared__ int s[SCAN_BS];
  int t = threadIdx.x;
  int g = blockIdx.x * SCAN_BS + t;
  int v = (g < n) ? deg[g] : 0;
  s[t] = v;
  __syncthreads();
  for (int off = 1; off < SCAN_BS; off <<= 1) {
    int add = (t >= off) ? s[t - off] : 0;
    __syncthreads();
    s[t] += add;
    __syncthreads();
  }
  if (g < n) exc[g] = s[t] - v;
  if (t == SCAN_BS - 1) partial[blockIdx.x] = s[t];
}

__global__ void scan2_kernel(int* __restrict__ partial, int nb) {
  __shared__ int s[SCAN_BS];
  int t = threadIdx.x;
  int v = (t < nb) ? partial[t] : 0;
  s[t] = v;
  __syncthreads();
  for (int off = 1; off < SCAN_BS; off <<= 1) {
    int add = (t >= off) ? s[t - off] : 0;
    __syncthreads();
    s[t] += add;
    __syncthreads();
  }
  if (t < nb) partial[t] = s[t] - v;
}

__global__ void scan3_kernel(const int* __restrict__ exc, const int* __restrict__ partial,
                             int* __restrict__ row_start, int* __restrict__ cursor,
                             int n, int E) {
  int g = blockIdx.x * blockDim.x + threadIdx.x;
  if (g < n) {
    int v = exc[g] + partial[g / SCAN_BS];
    row_start[g] = v;
    cursor[g] = v;
  }
  if (g == n) row_start[n] = E;
}

__global__ void scatter_kernel(const int* __restrict__ srcArr, const int* __restrict__ dstArr,
                               int* __restrict__ cursor, int* __restrict__ csr_src,
                               int* __restrict__ csr_dst, int E) {
  int e = blockIdx.x * blockDim.x + threadIdx.x;
  if (e < E) {
    int d = dstArr[e];
    int p = atomicAdd(&cursor[d], 1);
    csr_src[p] = srcArr[e];
    csr_dst[p] = d;
  }
}

// ---------------- weight prep: transpose + concat + bf16 hi/lo split ----------------
__global__ void wprep_kernel(const float* __restrict__ Wq, const float* __restrict__ Wk,
                             const float* __restrict__ Wv, const float* __restrict__ bq,
                             const float* __restrict__ bk, const float* __restrict__ bv,
                             unsigned short* __restrict__ Bth, unsigned short* __restrict__ Btl,
                             float* __restrict__ biascat, int L) {
  int idx = blockIdx.x * 256 + threadIdx.x;
  int total = L * QKVS * CC;
  if (idx >= total) return;
  int k = idx & 255;
  int n = (idx >> 8) % QKVS;
  int l = idx / (QKVS * CC);
  int part = n >> 8;
  int nn = n & 255;
  const float* W = part == 0 ? Wq : (part == 1 ? Wk : Wv);
  float v = W[((long)l * CC + k) * CC + nn];
  __bf16 h = (__bf16)v;
  Bth[idx] = __builtin_bit_cast(unsigned short, h);
  Btl[idx] = __builtin_bit_cast(unsigned short, (__bf16)(v - (float)h));
  if (k == 0) {
    const float* bb = part == 0 ? bq : (part == 1 ? bk : bv);
    biascat[l * QKVS + n] = bb[l * CC + nn];
  }
}

// ---------------- activation split: fp32 -> bf16 hi + lo (layer-0 input only) ------
__global__ void split_kernel(const float* __restrict__ in, unsigned short* __restrict__ hi,
                             unsigned short* __restrict__ lo, int n4) {
  int i = blockIdx.x * 256 + threadIdx.x;
  if (i >= n4) return;
  float4 v = ((const float4*)in)[i];
  __bf16 h0 = (__bf16)v.x, h1 = (__bf16)v.y, h2 = (__bf16)v.z, h3 = (__bf16)v.w;
  ushort4 hv = make_ushort4(__builtin_bit_cast(unsigned short, h0),
                            __builtin_bit_cast(unsigned short, h1),
                            __builtin_bit_cast(unsigned short, h2),
                            __builtin_bit_cast(unsigned short, h3));
  ushort4 lv = make_ushort4(__builtin_bit_cast(unsigned short, (__bf16)(v.x - (float)h0)),
                            __builtin_bit_cast(unsigned short, (__bf16)(v.y - (float)h1)),
                            __builtin_bit_cast(unsigned short, (__bf16)(v.z - (float)h2)),
                            __builtin_bit_cast(unsigned short, (__bf16)(v.w - (float)h3)));
  ((ushort4*)hi)[i] = hv;
  ((ushort4*)lo)[i] = lv;
}

// ---------------- fused QKV GEMM via split-bf16 MFMA ----------------
// C[M x 768] = (Ah+Al)[M x 256] @ (Bh+Bl)[256 x 768] + bias ~= Ah*Bh + Ah*Bl + Al*Bh.
// 128x128 tile, 4 waves (2x2 of 64x64), 16x16x32 bf16 MFMA.
__global__ __launch_bounds__(256) void qkv_gemm(const unsigned short* __restrict__ Ah,
                                                const unsigned short* __restrict__ Al,
                                                const unsigned short* __restrict__ Bh,
                                                const unsigned short* __restrict__ Bl,
                                                const float* __restrict__ biascat,
                                                float* __restrict__ C, int M) {
  __shared__ unsigned short As_h[128 * LDK], As_l[128 * LDK];
  __shared__ unsigned short Bs_h[128 * LDK], Bs_l[128 * LDK];
  int t = threadIdx.x;
  int bm = blockIdx.x, bn = blockIdx.y;
  int lane = t & 63, wave = t >> 6;
  int mo = (wave >> 1) * 64, no = (wave & 1) * 64;
  int col_l = lane & 15, q = lane >> 4;

  f32x4 acc[4][4];
#pragma unroll
  for (int i = 0; i < 4; ++i)
#pragma unroll
    for (int j = 0; j < 4; ++j) acc[i][j] = (f32x4)0.f;

  int sr = t >> 1;             // staging row 0..127
  int sh = (t & 1) * 16;       // k-half offset
  long arow = (long)bm * 128 + sr;
  bool aval = arow < M;
  const unsigned short* agh = Ah + arow * CC + sh;
  const unsigned short* agl = Al + arow * CC + sh;
  const unsigned short* bgh = Bh + ((long)bn * 128 + sr) * CC + sh;
  const unsigned short* bgl = Bl + ((long)bn * 128 + sr) * CC + sh;
  uint4 zz = make_uint4(0, 0, 0, 0);

  for (int kt = 0; kt < CC; kt += 32) {
    uint4 ah0 = zz, ah1 = zz, al0 = zz, al1 = zz;
    if (aval) {
      ah0 = *(const uint4*)(agh + kt);
      ah1 = *(const uint4*)(agh + kt + 8);
      al0 = *(const uint4*)(agl + kt);
      al1 = *(const uint4*)(agl + kt + 8);
    }
    uint4 bh0 = *(const uint4*)(bgh + kt);
    uint4 bh1 = *(const uint4*)(bgh + kt + 8);
    uint4 bl0 = *(const uint4*)(bgl + kt);
    uint4 bl1 = *(const uint4*)(bgl + kt + 8);
    __syncthreads();
    *(uint4*)&As_h[sr * LDK + sh] = ah0;
    *(uint4*)&As_h[sr * LDK + sh + 8] = ah1;
    *(uint4*)&As_l[sr * LDK + sh] = al0;
    *(uint4*)&As_l[sr * LDK + sh + 8] = al1;
    *(uint4*)&Bs_h[sr * LDK + sh] = bh0;
    *(uint4*)&Bs_h[sr * LDK + sh + 8] = bh1;
    *(uint4*)&Bs_l[sr * LDK + sh] = bl0;
    *(uint4*)&Bs_l[sr * LDK + sh + 8] = bl1;
    __syncthreads();

    s16x8 afh[4], afl[4], bfh[4], bfl[4];
#pragma unroll
    for (int i = 0; i < 4; ++i) {
      int am = mo + i * 16 + col_l;
      afh[i] = *(const s16x8*)&As_h[am * LDK + q * 8];
      afl[i] = *(const s16x8*)&As_l[am * LDK + q * 8];
      int bnn = no + i * 16 + col_l;
      bfh[i] = *(const s16x8*)&Bs_h[bnn * LDK + q * 8];
      bfl[i] = *(const s16x8*)&Bs_l[bnn * LDK + q * 8];
    }
#pragma unroll
    for (int i = 0; i < 4; ++i)
#pragma unroll
      for (int j = 0; j < 4; ++j) {
        acc[i][j] = __builtin_amdgcn_mfma_f32_16x16x32_bf16(afh[i], bfh[j], acc[i][j], 0, 0, 0);
        acc[i][j] = __builtin_amdgcn_mfma_f32_16x16x32_bf16(afh[i], bfl[j], acc[i][j], 0, 0, 0);
        acc[i][j] = __builtin_amdgcn_mfma_f32_16x16x32_bf16(afl[i], bfh[j], acc[i][j], 0, 0, 0);
      }
  }

  long rbase = (long)bm * 128 + mo;
  int cbase = bn * 128 + no;
#pragma unroll
  for (int j = 0; j < 4; ++j) {
    int col = cbase + j * 16 + col_l;
    float bias = biascat[col];
#pragma unroll
    for (int i = 0; i < 4; ++i) {
#pragma unroll
      for (int r = 0; r < 4; ++r) {
        long row = rbase + i * 16 + q * 4 + r;
        if (row < M) C[row * QKVS + col] = acc[i][j][r] + bias;
      }
    }
  }
}

// ---------------- attention phase 1: per-edge logits ----------------
__global__ __launch_bounds__(256) void edge_logits_kernel(const float* __restrict__ qkv,
                                                          const int* __restrict__ csr_src,
                                                          const int* __restrict__ csr_dst,
                                                          float* __restrict__ logits, int E) {
  int wave = threadIdx.x >> 6;
  int lane = threadIdx.x & 63;
  int e = blockIdx.x * 4 + wave;
  if (e >= E) return;
  int s = csr_src[e];
  int d = csr_dst[e];
  const float4 qv = *(const float4*)(qkv + (size_t)d * QKVS + lane * 4);          // Q at ofs 0
  const float4 kv = *(const float4*)(qkv + (size_t)s * QKVS + 256 + lane * 4);    // K at ofs 256
  float dot = qv.x * kv.x + qv.y * kv.y + qv.z * kv.z + qv.w * kv.w;
#pragma unroll
  for (int off = 1; off < 16; off <<= 1) dot += __shfl_xor(dot, off, 64);
  if ((lane & 15) == 0) {
    int h = lane >> 4;
    logits[(size_t)h * E + e] = dot * 0.125f;   // 1/sqrt(64)
  }
}

// ---------------- attention phase 2: segment softmax over CSR rows ----------------
__global__ void seg_softmax_kernel(float* __restrict__ w, const int* __restrict__ row_start,
                                   int N, int E) {
  int t = blockIdx.x * blockDim.x + threadIdx.x;
  if (t >= HEADS * N) return;
  int h = t / N;
  int n = t - h * N;
  float* plane = w + (size_t)h * E;
  int s0 = row_start[n], s1 = row_start[n + 1];
  if (s0 >= s1) return;
  float m = -1e30f, z = 0.f;
  for (int i = s0; i < s1; ++i) {
    float l = plane[i];
    float mn = fmaxf(m, l);
    z = z * expf(m - mn) + expf(l - mn);
    m = mn;
  }
  float rz = 1.f / z;
  for (int i = s0; i < s1; ++i) plane[i] = expf(plane[i] - m) * rz;
}

// ---------------- attention phase 3: weighted V aggregation + ReLU -> bf16 hi/lo ----
__global__ __launch_bounds__(256) void aggregate_kernel(const float* __restrict__ qkv,
                                                        const float* __restrict__ w,
                                                        const int* __restrict__ row_start,
                                                        const int* __restrict__ csr_src,
                                                        unsigned short* __restrict__ h_hi,
                                                        unsigned short* __restrict__ h_lo,
                                                        int E) {
  int node = blockIdx.x;
  int wave = threadIdx.x >> 6;
  int s0 = row_start[node], s1 = row_start[node + 1];
  const float* wplane = w + (size_t)wave * E;
  float acc = 0.f;
  for (int i = s0; i < s1; ++i) {
    int s = csr_src[i];
    float wt = wplane[i];
    acc = fmaf(wt, qkv[(size_t)s * QKVS + 512 + threadIdx.x], acc);   // V at ofs 512
  }
  float h = fmaxf(acc, 0.f);
  __bf16 hi = (__bf16)h;
  size_t idx = (size_t)node * CC + threadIdx.x;
  h_hi[idx] = __builtin_bit_cast(unsigned short, hi);
  h_lo[idx] = __builtin_bit_cast(unsigned short, (__bf16)(h - (float)hi));
}

// ---------------- pool: parallel segment-sum with atomics (batch sorted) ----------------
__global__ void pool_kernel(const unsigned short* __restrict__ h_hi,
                            const unsigned short* __restrict__ h_lo,
                            const int* __restrict__ batch,
                            float* __restrict__ gpool, int N) {
  int c = threadIdx.x;
  int n0 = blockIdx.x * 64;
  int n1 = min(n0 + 64, N);
  int cur = batch[n0];
  float acc = 0.f;
  for (int n = n0; n < n1; ++n) {
    int g = batch[n];
    if (g != cur) {
      atomicAdd(&gpool[cur * CC + c], acc);
      acc = 0.f;
      cur = g;
    }
    size_t idx = (size_t)n * CC + c;
    acc += bf2f(h_hi[idx]) + bf2f(h_lo[idx]);
  }
  atomicAdd(&gpool[cur * CC + c], acc);
}

// ---------------- MLP head ----------------
__global__ void head_kernel(const float* __restrict__ gpool, const float* __restrict__ W1,
                            const float* __restrict__ b1, const float* __restrict__ W2,
                            const float* __restrict__ b2, float* __restrict__ out) {
  __shared__ float hid[64];
  int g = blockIdx.x, t = threadIdx.x;
  float acc = b1[t];
  for (int i = 0; i < CC; ++i) acc = fmaf(gpool[g * CC + i], W1[i * 64 + t], acc);
  hid[t] = fmaxf(acc, 0.f);
  __syncthreads();
  if (t < 16) {
    float o = b2[t];
    for (int i = 0; i < 64; ++i) o = fmaf(hid[i], W2[i * 16 + t], o);
    out[g * 16 + t] = o;
  }
}

extern "C" void kernel_launch(void* const* d_in, const int* in_sizes, int n_in,
                              void* d_out, int out_size, void* d_ws, size_t ws_size,
                              hipStream_t stream) {
  const float* x  = (const float*)d_in[0];
  const int* ei   = (const int*)d_in[1];
  const int* batch = (const int*)d_in[2];
  const float* Wq = (const float*)d_in[3];
  const float* bq = (const float*)d_in[4];
  const float* Wk = (const float*)d_in[5];
  const float* bk = (const float*)d_in[6];
  const float* Wv = (const float*)d_in[7];
  const float* bv = (const float*)d_in[8];
  const float* W1 = (const float*)d_in[9];
  const float* b1 = (const float*)d_in[10];
  const float* W2 = (const float*)d_in[11];
  const float* b2 = (const float*)d_in[12];
  float* out = (float*)d_out;

  int N = in_sizes[0] / CC;
  int E = in_sizes[1] / 2;
  int L = in_sizes[3] / (CC * CC);
  const int* src = ei;
  const int* dst = ei + E;

  // workspace budget: keep total < 256 MB (R3 crashed at ~278 MB; R2 passed at ~225 MB)
  size_t off = 0;
  auto alloc = [&](size_t bytes) -> void* {
    void* p = (char*)d_ws + off;
    off += (bytes + 255) & ~(size_t)255;
    return p;
  };
  float* qkv = (float*)alloc((size_t)N * QKVS * 4);            // 153.6 MB
  unsigned short* h_hi = (unsigned short*)alloc((size_t)N * CC * 2);  // 25.6 MB
  unsigned short* h_lo = (unsigned short*)alloc((size_t)N * CC * 2);  // 25.6 MB
  unsigned short* Bth = (unsigned short*)alloc((size_t)L * QKVS * CC * 2);
  unsigned short* Btl = (unsigned short*)alloc((size_t)L * QKVS * CC * 2);
  float* biascat = (float*)alloc((size_t)L * QKVS * 4);
  int* deg = (int*)alloc((size_t)N * 4);
  int* exc = (int*)alloc((size_t)N * 4);
  int* partial = (int*)alloc(SCAN_BS * 4);
  int* row_start = (int*)alloc((size_t)(N + 1) * 4);
  int* cursor = (int*)alloc((size_t)N * 4);
  int* csr_src = (int*)alloc((size_t)E * 4);
  int* csr_dst = (int*)alloc((size_t)E * 4);
  float* wbuf = (float*)alloc((size_t)E * HEADS * 4);          // 12.8 MB
  float* gpool = (float*)alloc((size_t)NG * CC * 4);
  // total ~= 227 MB

  // CSR by dst
  hipMemsetAsync(deg, 0, (size_t)N * 4, stream);
  int eb = (E + 255) / 256;
  hist_kernel<<<eb, 256, 0, stream>>>(dst, deg, E);
  int nb = (N + SCAN_BS - 1) / SCAN_BS;
  scan1_kernel<<<nb, SCAN_BS, 0, stream>>>(deg, exc, partial, N);
  scan2_kernel<<<1, SCAN_BS, 0, stream>>>(partial, nb);
  scan3_kernel<<<(N + 1 + 255) / 256, 256, 0, stream>>>(exc, partial, row_start, cursor, N, E);
  scatter_kernel<<<eb, 256, 0, stream>>>(src, dst, cursor, csr_src, csr_dst, E);

  // weight prep (transpose + concat + hi/lo split)
  int wtot = L * QKVS * CC;
  wprep_kernel<<<(wtot + 255) / 256, 256, 0, stream>>>(Wq, Wk, Wv, bq, bk, bv,
                                                       Bth, Btl, biascat, L);

  // layer-0 input split
  int n4 = N * CC / 4;
  split_kernel<<<(n4 + 255) / 256, 256, 0, stream>>>(x, h_hi, h_lo, n4);

  // layers
  dim3 gemmGrid((N + 127) / 128, QKVS / 128);
  int ewb = (E + 3) / 4;
  int smb = (HEADS * N + 255) / 256;
  for (int l = 0; l < L; ++l) {
    qkv_gemm<<<gemmGrid, 256, 0, stream>>>(h_hi, h_lo,
                                           Bth + (size_t)l * QKVS * CC,
                                           Btl + (size_t)l * QKVS * CC,
                                           biascat + (size_t)l * QKVS, qkv, N);
    edge_logits_kernel<<<ewb, 256, 0, stream>>>(qkv, csr_src, csr_dst, wbuf, E);
    seg_softmax_kernel<<<smb, 256, 0, stream>>>(wbuf, row_start, N, E);
    aggregate_kernel<<<N, 256, 0, stream>>>(qkv, wbuf, row_start, csr_src, h_hi, h_lo, E);
  }

  // pool + head
  hipMemsetAsync(gpool, 0, (size_t)NG * CC * 4, stream);
  pool_kernel<<<(N + 63) / 64, 256, 0, stream>>>(h_hi, h_lo, batch, gpool, N);
  head_kernel<<<NG, 64, 0, stream>>>(gpool, W1, b1, W2, b2, out);
}

// Round 5
// 1379.082 us; speedup vs baseline: 1.6607x; 1.1754x over previous
//
#include <hip/hip_runtime.h>
#include <math.h>

#define CC 256       // channels = HEADS * HD
#define HEADS 4
#define HD 64
#define NG 64        // num graphs
#define SCAN_BS 512
#define QKVS 768     // fused QKV row stride
#define LDK 40       // padded LDS k-stride (bf16 elems)

typedef __attribute__((ext_vector_type(8))) short s16x8;   // 8 x bf16 (4 VGPRs)
typedef __attribute__((ext_vector_type(4))) float f32x4;

static __device__ __forceinline__ float bf2f(unsigned short u) {
  return (float)__builtin_bit_cast(__bf16, u);
}

// ---------------- CSR build (by dst) ----------------
__global__ void hist_kernel(const int* __restrict__ dst, int* __restrict__ deg, int E) {
  int e = blockIdx.x * blockDim.x + threadIdx.x;
  if (e < E) atomicAdd(&deg[dst[e]], 1);
}

__global__ void scan1_kernel(const int* __restrict__ deg, int* __restrict__ exc,
                             int* __restrict__ partial, int n) {
  __shared__ int s[SCAN_BS];
  int t = threadIdx.x;
  int g = blockIdx.x * SCAN_BS + t;
  int v = (g < n) ? deg[g] : 0;
  s[t] = v;
  __syncthreads();
  for (int off = 1; off < SCAN_BS; off <<= 1) {
    int add = (t >= off) ? s[t - off] : 0;
    __syncthreads();
    s[t] += add;
    __syncthreads();
  }
  if (g < n) exc[g] = s[t] - v;
  if (t == SCAN_BS - 1) partial[blockIdx.x] = s[t];
}

__global__ void scan2_kernel(int* __restrict__ partial, int nb) {
  __shared__ int s[SCAN_BS];
  int t = threadIdx.x;
  int v = (t < nb) ? partial[t] : 0;
  s[t] = v;
  __syncthreads();
  for (int off = 1; off < SCAN_BS; off <<= 1) {
    int add = (t >= off) ? s[t - off] : 0;
    __syncthreads();
    s[t] += add;
    __syncthreads();
  }
  if (t < nb) partial[t] = s[t] - v;
}

__global__ void scan3_kernel(const int* __restrict__ exc, const int* __restrict__ partial,
                             int* __restrict__ row_start, int* __restrict__ cursor,
                             int n, int E) {
  int g = blockIdx.x * blockDim.x + threadIdx.x;
  if (g < n) {
    int v = exc[g] + partial[g / SCAN_BS];
    row_start[g] = v;
    cursor[g] = v;
  }
  if (g == n) row_start[n] = E;
}

__global__ void scatter_kernel(const int* __restrict__ srcArr, const int* __restrict__ dstArr,
                               int* __restrict__ cursor, int* __restrict__ csr_src,
                               int* __restrict__ csr_dst, int E) {
  int e = blockIdx.x * blockDim.x + threadIdx.x;
  if (e < E) {
    int d = dstArr[e];
    int p = atomicAdd(&cursor[d], 1);
    csr_src[p] = srcArr[e];
    csr_dst[p] = d;
  }
}

// ---------------- weight prep: transpose + concat + bf16 hi/lo split ----------------
__global__ void wprep_kernel(const float* __restrict__ Wq, const float* __restrict__ Wk,
                             const float* __restrict__ Wv, const float* __restrict__ bq,
                             const float* __restrict__ bk, const float* __restrict__ bv,
                             unsigned short* __restrict__ Bth, unsigned short* __restrict__ Btl,
                             float* __restrict__ biascat, int L) {
  int idx = blockIdx.x * 256 + threadIdx.x;
  int total = L * QKVS * CC;
  if (idx >= total) return;
  int k = idx & 255;
  int n = (idx >> 8) % QKVS;
  int l = idx / (QKVS * CC);
  int part = n >> 8;
  int nn = n & 255;
  const float* W = part == 0 ? Wq : (part == 1 ? Wk : Wv);
  float v = W[((long)l * CC + k) * CC + nn];
  __bf16 h = (__bf16)v;
  Bth[idx] = __builtin_bit_cast(unsigned short, h);
  Btl[idx] = __builtin_bit_cast(unsigned short, (__bf16)(v - (float)h));
  if (k == 0) {
    const float* bb = part == 0 ? bq : (part == 1 ? bk : bv);
    biascat[l * QKVS + n] = bb[l * CC + nn];
  }
}

// ---------------- activation split: fp32 -> bf16 hi + lo (layer-0 input only) ------
__global__ void split_kernel(const float* __restrict__ in, unsigned short* __restrict__ hi,
                             unsigned short* __restrict__ lo, int n4) {
  int i = blockIdx.x * 256 + threadIdx.x;
  if (i >= n4) return;
  float4 v = ((const float4*)in)[i];
  __bf16 h0 = (__bf16)v.x, h1 = (__bf16)v.y, h2 = (__bf16)v.z, h3 = (__bf16)v.w;
  ushort4 hv = make_ushort4(__builtin_bit_cast(unsigned short, h0),
                            __builtin_bit_cast(unsigned short, h1),
                            __builtin_bit_cast(unsigned short, h2),
                            __builtin_bit_cast(unsigned short, h3));
  ushort4 lv = make_ushort4(__builtin_bit_cast(unsigned short, (__bf16)(v.x - (float)h0)),
                            __builtin_bit_cast(unsigned short, (__bf16)(v.y - (float)h1)),
                            __builtin_bit_cast(unsigned short, (__bf16)(v.z - (float)h2)),
                            __builtin_bit_cast(unsigned short, (__bf16)(v.w - (float)h3)));
  ((ushort4*)hi)[i] = hv;
  ((ushort4*)lo)[i] = lv;
}

// ---------------- fused QKV GEMM via split-bf16 MFMA ----------------
__global__ __launch_bounds__(256) void qkv_gemm(const unsigned short* __restrict__ Ah,
                                                const unsigned short* __restrict__ Al,
                                                const unsigned short* __restrict__ Bh,
                                                const unsigned short* __restrict__ Bl,
                                                const float* __restrict__ biascat,
                                                float* __restrict__ C, int M) {
  __shared__ unsigned short As_h[128 * LDK], As_l[128 * LDK];
  __shared__ unsigned short Bs_h[128 * LDK], Bs_l[128 * LDK];
  int t = threadIdx.x;
  int bm = blockIdx.x, bn = blockIdx.y;
  int lane = t & 63, wave = t >> 6;
  int mo = (wave >> 1) * 64, no = (wave & 1) * 64;
  int col_l = lane & 15, q = lane >> 4;

  f32x4 acc[4][4];
#pragma unroll
  for (int i = 0; i < 4; ++i)
#pragma unroll
    for (int j = 0; j < 4; ++j) acc[i][j] = (f32x4)0.f;

  int sr = t >> 1;
  int sh = (t & 1) * 16;
  long arow = (long)bm * 128 + sr;
  bool aval = arow < M;
  const unsigned short* agh = Ah + arow * CC + sh;
  const unsigned short* agl = Al + arow * CC + sh;
  const unsigned short* bgh = Bh + ((long)bn * 128 + sr) * CC + sh;
  const unsigned short* bgl = Bl + ((long)bn * 128 + sr) * CC + sh;
  uint4 zz = make_uint4(0, 0, 0, 0);

  for (int kt = 0; kt < CC; kt += 32) {
    uint4 ah0 = zz, ah1 = zz, al0 = zz, al1 = zz;
    if (aval) {
      ah0 = *(const uint4*)(agh + kt);
      ah1 = *(const uint4*)(agh + kt + 8);
      al0 = *(const uint4*)(agl + kt);
      al1 = *(const uint4*)(agl + kt + 8);
    }
    uint4 bh0 = *(const uint4*)(bgh + kt);
    uint4 bh1 = *(const uint4*)(bgh + kt + 8);
    uint4 bl0 = *(const uint4*)(bgl + kt);
    uint4 bl1 = *(const uint4*)(bgl + kt + 8);
    __syncthreads();
    *(uint4*)&As_h[sr * LDK + sh] = ah0;
    *(uint4*)&As_h[sr * LDK + sh + 8] = ah1;
    *(uint4*)&As_l[sr * LDK + sh] = al0;
    *(uint4*)&As_l[sr * LDK + sh + 8] = al1;
    *(uint4*)&Bs_h[sr * LDK + sh] = bh0;
    *(uint4*)&Bs_h[sr * LDK + sh + 8] = bh1;
    *(uint4*)&Bs_l[sr * LDK + sh] = bl0;
    *(uint4*)&Bs_l[sr * LDK + sh + 8] = bl1;
    __syncthreads();

    s16x8 afh[4], afl[4], bfh[4], bfl[4];
#pragma unroll
    for (int i = 0; i < 4; ++i) {
      int am = mo + i * 16 + col_l;
      afh[i] = *(const s16x8*)&As_h[am * LDK + q * 8];
      afl[i] = *(const s16x8*)&As_l[am * LDK + q * 8];
      int bnn = no + i * 16 + col_l;
      bfh[i] = *(const s16x8*)&Bs_h[bnn * LDK + q * 8];
      bfl[i] = *(const s16x8*)&Bs_l[bnn * LDK + q * 8];
    }
#pragma unroll
    for (int i = 0; i < 4; ++i)
#pragma unroll
      for (int j = 0; j < 4; ++j) {
        acc[i][j] = __builtin_amdgcn_mfma_f32_16x16x32_bf16(afh[i], bfh[j], acc[i][j], 0, 0, 0);
        acc[i][j] = __builtin_amdgcn_mfma_f32_16x16x32_bf16(afh[i], bfl[j], acc[i][j], 0, 0, 0);
        acc[i][j] = __builtin_amdgcn_mfma_f32_16x16x32_bf16(afl[i], bfh[j], acc[i][j], 0, 0, 0);
      }
  }

  long rbase = (long)bm * 128 + mo;
  int cbase = bn * 128 + no;
#pragma unroll
  for (int j = 0; j < 4; ++j) {
    int col = cbase + j * 16 + col_l;
    float bias = biascat[col];
#pragma unroll
    for (int i = 0; i < 4; ++i) {
#pragma unroll
      for (int r = 0; r < 4; ++r) {
        long row = rbase + i * 16 + q * 4 + r;
        if (row < M) C[row * QKVS + col] = acc[i][j][r] + bias;
      }
    }
  }
}

// ---------------- attention phase 1: per-edge logits (2 edges per wave for MLP) ----
__global__ __launch_bounds__(256) void edge_logits_kernel(const float* __restrict__ qkv,
                                                          const int* __restrict__ csr_src,
                                                          const int* __restrict__ csr_dst,
                                                          float* __restrict__ logits, int E) {
  int wave = threadIdx.x >> 6;
  int lane = threadIdx.x & 63;
  int e0 = blockIdx.x * 8 + wave;
  int e1 = e0 + 4;
  bool v0 = e0 < E, v1 = e1 < E;
  int s0i = v0 ? csr_src[e0] : 0;
  int d0i = v0 ? csr_dst[e0] : 0;
  int s1i = v1 ? csr_src[e1] : 0;
  int d1i = v1 ? csr_dst[e1] : 0;
  // 4 independent loads in flight; lane*4 covers the full 1 KB row
  const float4 q0 = *(const float4*)(qkv + (size_t)d0i * QKVS + lane * 4);
  const float4 k0 = *(const float4*)(qkv + (size_t)s0i * QKVS + 256 + lane * 4);
  const float4 q1 = *(const float4*)(qkv + (size_t)d1i * QKVS + lane * 4);
  const float4 k1 = *(const float4*)(qkv + (size_t)s1i * QKVS + 256 + lane * 4);
  float dot0 = q0.x * k0.x + q0.y * k0.y + q0.z * k0.z + q0.w * k0.w;
  float dot1 = q1.x * k1.x + q1.y * k1.y + q1.z * k1.z + q1.w * k1.w;
#pragma unroll
  for (int off = 1; off < 16; off <<= 1) {
    dot0 += __shfl_xor(dot0, off, 64);
    dot1 += __shfl_xor(dot1, off, 64);
  }
  if ((lane & 15) == 0) {
    int h = lane >> 4;
    if (v0) logits[(size_t)h * E + e0] = dot0 * 0.125f;
    if (v1) logits[(size_t)h * E + e1] = dot1 * 0.125f;
  }
}

// ---------------- attention phase 2: segment max/sum -> (m, 1/z) ----------------
__global__ void seg_softmax_kernel(const float* __restrict__ w, const int* __restrict__ row_start,
                                   float2* __restrict__ mz, int N, int E) {
  int t = blockIdx.x * blockDim.x + threadIdx.x;
  if (t >= HEADS * N) return;
  int h = t / N;
  int n = t - h * N;
  const float* plane = w + (size_t)h * E;
  int s0 = row_start[n], s1 = row_start[n + 1];
  if (s0 >= s1) return;
  // two online accumulators for ILP, merged at the end
  float m1 = -1e30f, z1 = 0.f, m2 = -1e30f, z2 = 0.f;
  int i = s0;
  for (; i + 2 <= s1; i += 2) {
    float la = plane[i], lb = plane[i + 1];
    float mn1 = fmaxf(m1, la);
    z1 = z1 * __expf(m1 - mn1) + __expf(la - mn1);
    m1 = mn1;
    float mn2 = fmaxf(m2, lb);
    z2 = z2 * __expf(m2 - mn2) + __expf(lb - mn2);
    m2 = mn2;
  }
  if (i < s1) {
    float la = plane[i];
    float mn1 = fmaxf(m1, la);
    z1 = z1 * __expf(m1 - mn1) + __expf(la - mn1);
    m1 = mn1;
  }
  float m = fmaxf(m1, m2);
  float z = z1 * __expf(m1 - m) + z2 * __expf(m2 - m);
  mz[(size_t)h * N + n] = make_float2(m, 1.f / (z + 1e-16f));
}

// ---------------- attention phase 3: fused normalize + V aggregation + ReLU -------
// block = node, wave = head; 4x unrolled gather keeps 4 V-row loads in flight.
__global__ __launch_bounds__(256) void aggregate_kernel(const float* __restrict__ qkv,
                                                        const float* __restrict__ logits,
                                                        const float2* __restrict__ mz,
                                                        const int* __restrict__ row_start,
                                                        const int* __restrict__ csr_src,
                                                        unsigned short* __restrict__ h_hi,
                                                        unsigned short* __restrict__ h_lo,
                                                        int N, int E) {
  int node = blockIdx.x;
  int wave = threadIdx.x >> 6;
  int s0 = row_start[node], s1 = row_start[node + 1];
  float h = 0.f;
  if (s1 > s0) {
    float2 p = mz[(size_t)wave * N + node];
    float m = p.x, rz = p.y;
    const float* lp = logits + (size_t)wave * E;
    const float* vbase = qkv + 512 + threadIdx.x;
    float acc = 0.f;
    int i = s0;
    for (; i + 4 <= s1; i += 4) {
      int a = csr_src[i], b = csr_src[i + 1], c = csr_src[i + 2], d = csr_src[i + 3];
      float la = lp[i], lb = lp[i + 1], lc = lp[i + 2], ld = lp[i + 3];
      float va = vbase[(size_t)a * QKVS];
      float vb = vbase[(size_t)b * QKVS];
      float vc = vbase[(size_t)c * QKVS];
      float vd = vbase[(size_t)d * QKVS];
      float wa = __expf(la - m) * rz;
      float wb = __expf(lb - m) * rz;
      float wc = __expf(lc - m) * rz;
      float wd = __expf(ld - m) * rz;
      acc = fmaf(wa, va, acc);
      acc = fmaf(wb, vb, acc);
      acc = fmaf(wc, vc, acc);
      acc = fmaf(wd, vd, acc);
    }
    for (; i < s1; ++i) {
      int a = csr_src[i];
      float wt = __expf(lp[i] - m) * rz;
      acc = fmaf(wt, vbase[(size_t)a * QKVS], acc);
    }
    h = fmaxf(acc, 0.f);
  }
  __bf16 hi = (__bf16)h;
  size_t idx = (size_t)node * CC + threadIdx.x;
  h_hi[idx] = __builtin_bit_cast(unsigned short, hi);
  h_lo[idx] = __builtin_bit_cast(unsigned short, (__bf16)(h - (float)hi));
}

// ---------------- pool: parallel segment-sum with atomics (batch sorted) ----------------
__global__ void pool_kernel(const unsigned short* __restrict__ h_hi,
                            const unsigned short* __restrict__ h_lo,
                            const int* __restrict__ batch,
                            float* __restrict__ gpool, int N) {
  int c = threadIdx.x;
  int n0 = blockIdx.x * 64;
  int n1 = min(n0 + 64, N);
  int cur = batch[n0];
  float acc = 0.f;
  for (int n = n0; n < n1; ++n) {
    int g = batch[n];
    if (g != cur) {
      atomicAdd(&gpool[cur * CC + c], acc);
      acc = 0.f;
      cur = g;
    }
    size_t idx = (size_t)n * CC + c;
    acc += bf2f(h_hi[idx]) + bf2f(h_lo[idx]);
  }
  atomicAdd(&gpool[cur * CC + c], acc);
}

// ---------------- MLP head ----------------
__global__ void head_kernel(const float* __restrict__ gpool, const float* __restrict__ W1,
                            const float* __restrict__ b1, const float* __restrict__ W2,
                            const float* __restrict__ b2, float* __restrict__ out) {
  __shared__ float hid[64];
  int g = blockIdx.x, t = threadIdx.x;
  float acc = b1[t];
  for (int i = 0; i < CC; ++i) acc = fmaf(gpool[g * CC + i], W1[i * 64 + t], acc);
  hid[t] = fmaxf(acc, 0.f);
  __syncthreads();
  if (t < 16) {
    float o = b2[t];
    for (int i = 0; i < 64; ++i) o = fmaf(hid[i], W2[i * 16 + t], o);
    out[g * 16 + t] = o;
  }
}

extern "C" void kernel_launch(void* const* d_in, const int* in_sizes, int n_in,
                              void* d_out, int out_size, void* d_ws, size_t ws_size,
                              hipStream_t stream) {
  const float* x  = (const float*)d_in[0];
  const int* ei   = (const int*)d_in[1];
  const int* batch = (const int*)d_in[2];
  const float* Wq = (const float*)d_in[3];
  const float* bq = (const float*)d_in[4];
  const float* Wk = (const float*)d_in[5];
  const float* bk = (const float*)d_in[6];
  const float* Wv = (const float*)d_in[7];
  const float* bv = (const float*)d_in[8];
  const float* W1 = (const float*)d_in[9];
  const float* b1 = (const float*)d_in[10];
  const float* W2 = (const float*)d_in[11];
  const float* b2 = (const float*)d_in[12];
  float* out = (float*)d_out;

  int N = in_sizes[0] / CC;
  int E = in_sizes[1] / 2;
  int L = in_sizes[3] / (CC * CC);
  const int* src = ei;
  const int* dst = ei + E;

  // workspace budget: keep total < 256 MB (R3 crashed at ~278 MB)
  size_t off = 0;
  auto alloc = [&](size_t bytes) -> void* {
    void* p = (char*)d_ws + off;
    off += (bytes + 255) & ~(size_t)255;
    return p;
  };
  float* qkv = (float*)alloc((size_t)N * QKVS * 4);                   // 153.6 MB
  unsigned short* h_hi = (unsigned short*)alloc((size_t)N * CC * 2);  // 25.6 MB
  unsigned short* h_lo = (unsigned short*)alloc((size_t)N * CC * 2);  // 25.6 MB
  unsigned short* Bth = (unsigned short*)alloc((size_t)L * QKVS * CC * 2);
  unsigned short* Btl = (unsigned short*)alloc((size_t)L * QKVS * CC * 2);
  float* biascat = (float*)alloc((size_t)L * QKVS * 4);
  int* deg = (int*)alloc((size_t)N * 4);
  int* exc = (int*)alloc((size_t)N * 4);
  int* partial = (int*)alloc(SCAN_BS * 4);
  int* row_start = (int*)alloc((size_t)(N + 1) * 4);
  int* cursor = (int*)alloc((size_t)N * 4);
  int* csr_src = (int*)alloc((size_t)E * 4);
  int* csr_dst = (int*)alloc((size_t)E * 4);
  float* wbuf = (float*)alloc((size_t)E * HEADS * 4);                 // 12.8 MB
  float2* mz = (float2*)alloc((size_t)HEADS * N * 8);                 // 1.6 MB
  float* gpool = (float*)alloc((size_t)NG * CC * 4);
  // total ~= 229 MB

  // CSR by dst
  hipMemsetAsync(deg, 0, (size_t)N * 4, stream);
  int eb = (E + 255) / 256;
  hist_kernel<<<eb, 256, 0, stream>>>(dst, deg, E);
  int nb = (N + SCAN_BS - 1) / SCAN_BS;
  scan1_kernel<<<nb, SCAN_BS, 0, stream>>>(deg, exc, partial, N);
  scan2_kernel<<<1, SCAN_BS, 0, stream>>>(partial, nb);
  scan3_kernel<<<(N + 1 + 255) / 256, 256, 0, stream>>>(exc, partial, row_start, cursor, N, E);
  scatter_kernel<<<eb, 256, 0, stream>>>(src, dst, cursor, csr_src, csr_dst, E);

  // weight prep (transpose + concat + hi/lo split)
  int wtot = L * QKVS * CC;
  wprep_kernel<<<(wtot + 255) / 256, 256, 0, stream>>>(Wq, Wk, Wv, bq, bk, bv,
                                                       Bth, Btl, biascat, L);

  // layer-0 input split
  int n4 = N * CC / 4;
  split_kernel<<<(n4 + 255) / 256, 256, 0, stream>>>(x, h_hi, h_lo, n4);

  // layers
  dim3 gemmGrid((N + 127) / 128, QKVS / 128);
  int ewb = (E + 7) / 8;
  int smb = (HEADS * N + 255) / 256;
  for (int l = 0; l < L; ++l) {
    qkv_gemm<<<gemmGrid, 256, 0, stream>>>(h_hi, h_lo,
                                           Bth + (size_t)l * QKVS * CC,
                                           Btl + (size_t)l * QKVS * CC,
                                           biascat + (size_t)l * QKVS, qkv, N);
    edge_logits_kernel<<<ewb, 256, 0, stream>>>(qkv, csr_src, csr_dst, wbuf, E);
    seg_softmax_kernel<<<smb, 256, 0, stream>>>(wbuf, row_start, mz, N, E);
    aggregate_kernel<<<N, 256, 0, stream>>>(qkv, wbuf, mz, row_start, csr_src,
                                            h_hi, h_lo, N, E);
  }

  // pool + head
  hipMemsetAsync(gpool, 0, (size_t)NG * CC * 4, stream);
  pool_kernel<<<(N + 63) / 64, 256, 0, stream>>>(h_hi, h_lo, batch, gpool, N);
  head_kernel<<<NG, 64, 0, stream>>>(gpool, W1, b1, W2, b2, out);
}

// Round 6
// 1322.683 us; speedup vs baseline: 1.7315x; 1.0426x over previous
//
#include <hip/hip_runtime.h>
#include <math.h>

#define CC 256       // channels = HEADS * HD
#define HEADS 4
#define HD 64
#define NG 64        // num graphs
#define SCAN_BS 512
#define QKVS 768     // fused QKV row stride
#define LDK 40       // padded LDS k-stride (bf16 elems): 2-way bank aliasing only (free, m136)

typedef __attribute__((ext_vector_type(8))) short s16x8;   // 8 x bf16 (4 VGPRs)
typedef __attribute__((ext_vector_type(4))) float f32x4;

static __device__ __forceinline__ float bf2f(unsigned short u) {
  return (float)__builtin_bit_cast(__bf16, u);
}

// ---------------- CSR build (by dst) ----------------
__global__ void hist_kernel(const int* __restrict__ dst, int* __restrict__ deg, int E) {
  int e = blockIdx.x * blockDim.x + threadIdx.x;
  if (e < E) atomicAdd(&deg[dst[e]], 1);
}

__global__ void scan1_kernel(const int* __restrict__ deg, int* __restrict__ exc,
                             int* __restrict__ partial, int n) {
  __shared__ int s[SCAN_BS];
  int t = threadIdx.x;
  int g = blockIdx.x * SCAN_BS + t;
  int v = (g < n) ? deg[g] : 0;
  s[t] = v;
  __syncthreads();
  for (int off = 1; off < SCAN_BS; off <<= 1) {
    int add = (t >= off) ? s[t - off] : 0;
    __syncthreads();
    s[t] += add;
    __syncthreads();
  }
  if (g < n) exc[g] = s[t] - v;
  if (t == SCAN_BS - 1) partial[blockIdx.x] = s[t];
}

__global__ void scan2_kernel(int* __restrict__ partial, int nb) {
  __shared__ int s[SCAN_BS];
  int t = threadIdx.x;
  int v = (t < nb) ? partial[t] : 0;
  s[t] = v;
  __syncthreads();
  for (int off = 1; off < SCAN_BS; off <<= 1) {
    int add = (t >= off) ? s[t - off] : 0;
    __syncthreads();
    s[t] += add;
    __syncthreads();
  }
  if (t < nb) partial[t] = s[t] - v;
}

__global__ void scan3_kernel(const int* __restrict__ exc, const int* __restrict__ partial,
                             int* __restrict__ row_start, int* __restrict__ cursor,
                             int n, int E) {
  int g = blockIdx.x * blockDim.x + threadIdx.x;
  if (g < n) {
    int v = exc[g] + partial[g / SCAN_BS];
    row_start[g] = v;
    cursor[g] = v;
  }
  if (g == n) row_start[n] = E;
}

__global__ void scatter_kernel(const int* __restrict__ srcArr, const int* __restrict__ dstArr,
                               int* __restrict__ cursor, int* __restrict__ csr_src,
                               int* __restrict__ csr_dst, int E) {
  int e = blockIdx.x * blockDim.x + threadIdx.x;
  if (e < E) {
    int d = dstArr[e];
    int p = atomicAdd(&cursor[d], 1);
    csr_src[p] = srcArr[e];
    csr_dst[p] = d;
  }
}

// ---------------- weight prep: transpose + concat + bf16 hi/lo split ----------------
__global__ void wprep_kernel(const float* __restrict__ Wq, const float* __restrict__ Wk,
                             const float* __restrict__ Wv, const float* __restrict__ bq,
                             const float* __restrict__ bk, const float* __restrict__ bv,
                             unsigned short* __restrict__ Bth, unsigned short* __restrict__ Btl,
                             float* __restrict__ biascat, int L) {
  int idx = blockIdx.x * 256 + threadIdx.x;
  int total = L * QKVS * CC;
  if (idx >= total) return;
  int k = idx & 255;
  int n = (idx >> 8) % QKVS;
  int l = idx / (QKVS * CC);
  int part = n >> 8;
  int nn = n & 255;
  const float* W = part == 0 ? Wq : (part == 1 ? Wk : Wv);
  float v = W[((long)l * CC + k) * CC + nn];
  __bf16 h = (__bf16)v;
  Bth[idx] = __builtin_bit_cast(unsigned short, h);
  Btl[idx] = __builtin_bit_cast(unsigned short, (__bf16)(v - (float)h));
  if (k == 0) {
    const float* bb = part == 0 ? bq : (part == 1 ? bk : bv);
    biascat[l * QKVS + n] = bb[l * CC + nn];
  }
}

// ---------------- activation split: fp32 -> bf16 hi + lo (layer-0 input only) ------
__global__ void split_kernel(const float* __restrict__ in, unsigned short* __restrict__ hi,
                             unsigned short* __restrict__ lo, int n4) {
  int i = blockIdx.x * 256 + threadIdx.x;
  if (i >= n4) return;
  float4 v = ((const float4*)in)[i];
  __bf16 h0 = (__bf16)v.x, h1 = (__bf16)v.y, h2 = (__bf16)v.z, h3 = (__bf16)v.w;
  ushort4 hv = make_ushort4(__builtin_bit_cast(unsigned short, h0),
                            __builtin_bit_cast(unsigned short, h1),
                            __builtin_bit_cast(unsigned short, h2),
                            __builtin_bit_cast(unsigned short, h3));
  ushort4 lv = make_ushort4(__builtin_bit_cast(unsigned short, (__bf16)(v.x - (float)h0)),
                            __builtin_bit_cast(unsigned short, (__bf16)(v.y - (float)h1)),
                            __builtin_bit_cast(unsigned short, (__bf16)(v.z - (float)h2)),
                            __builtin_bit_cast(unsigned short, (__bf16)(v.w - (float)h3)));
  ((ushort4*)hi)[i] = hv;
  ((ushort4*)lo)[i] = lv;
}

// ---------------- fused QKV GEMM via split-bf16 MFMA ----------------
__global__ __launch_bounds__(256) void qkv_gemm(const unsigned short* __restrict__ Ah,
                                                const unsigned short* __restrict__ Al,
                                                const unsigned short* __restrict__ Bh,
                                                const unsigned short* __restrict__ Bl,
                                                const float* __restrict__ biascat,
                                                float* __restrict__ C, int M) {
  __shared__ unsigned short As_h[128 * LDK], As_l[128 * LDK];
  __shared__ unsigned short Bs_h[128 * LDK], Bs_l[128 * LDK];
  int t = threadIdx.x;
  int bm = blockIdx.x, bn = blockIdx.y;
  int lane = t & 63, wave = t >> 6;
  int mo = (wave >> 1) * 64, no = (wave & 1) * 64;
  int col_l = lane & 15, q = lane >> 4;

  f32x4 acc[4][4];
#pragma unroll
  for (int i = 0; i < 4; ++i)
#pragma unroll
    for (int j = 0; j < 4; ++j) acc[i][j] = (f32x4)0.f;

  int sr = t >> 1;
  int sh = (t & 1) * 16;
  long arow = (long)bm * 128 + sr;
  bool aval = arow < M;
  const unsigned short* agh = Ah + arow * CC + sh;
  const unsigned short* agl = Al + arow * CC + sh;
  const unsigned short* bgh = Bh + ((long)bn * 128 + sr) * CC + sh;
  const unsigned short* bgl = Bl + ((long)bn * 128 + sr) * CC + sh;
  uint4 zz = make_uint4(0, 0, 0, 0);

  for (int kt = 0; kt < CC; kt += 32) {
    uint4 ah0 = zz, ah1 = zz, al0 = zz, al1 = zz;
    if (aval) {
      ah0 = *(const uint4*)(agh + kt);
      ah1 = *(const uint4*)(agh + kt + 8);
      al0 = *(const uint4*)(agl + kt);
      al1 = *(const uint4*)(agl + kt + 8);
    }
    uint4 bh0 = *(const uint4*)(bgh + kt);
    uint4 bh1 = *(const uint4*)(bgh + kt + 8);
    uint4 bl0 = *(const uint4*)(bgl + kt);
    uint4 bl1 = *(const uint4*)(bgl + kt + 8);
    __syncthreads();
    *(uint4*)&As_h[sr * LDK + sh] = ah0;
    *(uint4*)&As_h[sr * LDK + sh + 8] = ah1;
    *(uint4*)&As_l[sr * LDK + sh] = al0;
    *(uint4*)&As_l[sr * LDK + sh + 8] = al1;
    *(uint4*)&Bs_h[sr * LDK + sh] = bh0;
    *(uint4*)&Bs_h[sr * LDK + sh + 8] = bh1;
    *(uint4*)&Bs_l[sr * LDK + sh] = bl0;
    *(uint4*)&Bs_l[sr * LDK + sh + 8] = bl1;
    __syncthreads();

    s16x8 afh[4], afl[4], bfh[4], bfl[4];
#pragma unroll
    for (int i = 0; i < 4; ++i) {
      int am = mo + i * 16 + col_l;
      afh[i] = *(const s16x8*)&As_h[am * LDK + q * 8];
      afl[i] = *(const s16x8*)&As_l[am * LDK + q * 8];
      int bnn = no + i * 16 + col_l;
      bfh[i] = *(const s16x8*)&Bs_h[bnn * LDK + q * 8];
      bfl[i] = *(const s16x8*)&Bs_l[bnn * LDK + q * 8];
    }
#pragma unroll
    for (int i = 0; i < 4; ++i)
#pragma unroll
      for (int j = 0; j < 4; ++j) {
        acc[i][j] = __builtin_amdgcn_mfma_f32_16x16x32_bf16(afh[i], bfh[j], acc[i][j], 0, 0, 0);
        acc[i][j] = __builtin_amdgcn_mfma_f32_16x16x32_bf16(afh[i], bfl[j], acc[i][j], 0, 0, 0);
        acc[i][j] = __builtin_amdgcn_mfma_f32_16x16x32_bf16(afl[i], bfh[j], acc[i][j], 0, 0, 0);
      }
  }

  long rbase = (long)bm * 128 + mo;
  int cbase = bn * 128 + no;
#pragma unroll
  for (int j = 0; j < 4; ++j) {
    int col = cbase + j * 16 + col_l;
    float bias = biascat[col];
#pragma unroll
    for (int i = 0; i < 4; ++i) {
#pragma unroll
      for (int r = 0; r < 4; ++r) {
        long row = rbase + i * 16 + q * 4 + r;
        if (row < M) C[row * QKVS + col] = acc[i][j][r] + bias;
      }
    }
  }
}

// ---------------- attention phase 1: per-edge logits (4 edges per wave for MLP) ----
__global__ __launch_bounds__(256) void edge_logits_kernel(const float* __restrict__ qkv,
                                                          const int* __restrict__ csr_src,
                                                          const int* __restrict__ csr_dst,
                                                          float* __restrict__ logits, int E) {
  int wave = threadIdx.x >> 6;
  int lane = threadIdx.x & 63;
  int base = blockIdx.x * 16 + wave;
  int e0 = base, e1 = base + 4, e2 = base + 8, e3 = base + 12;
  bool v0 = e0 < E, v1 = e1 < E, v2 = e2 < E, v3 = e3 < E;
  int s0i = v0 ? csr_src[e0] : 0;
  int s1i = v1 ? csr_src[e1] : 0;
  int s2i = v2 ? csr_src[e2] : 0;
  int s3i = v3 ? csr_src[e3] : 0;
  int d0i = v0 ? csr_dst[e0] : 0;
  int d1i = v1 ? csr_dst[e1] : 0;
  int d2i = v2 ? csr_dst[e2] : 0;
  int d3i = v3 ? csr_dst[e3] : 0;
  // 8 independent 1KB-row loads in flight; lane*4 covers the full row
  const float4 q0 = *(const float4*)(qkv + (size_t)d0i * QKVS + lane * 4);
  const float4 k0 = *(const float4*)(qkv + (size_t)s0i * QKVS + 256 + lane * 4);
  const float4 q1 = *(const float4*)(qkv + (size_t)d1i * QKVS + lane * 4);
  const float4 k1 = *(const float4*)(qkv + (size_t)s1i * QKVS + 256 + lane * 4);
  const float4 q2 = *(const float4*)(qkv + (size_t)d2i * QKVS + lane * 4);
  const float4 k2 = *(const float4*)(qkv + (size_t)s2i * QKVS + 256 + lane * 4);
  const float4 q3 = *(const float4*)(qkv + (size_t)d3i * QKVS + lane * 4);
  const float4 k3 = *(const float4*)(qkv + (size_t)s3i * QKVS + 256 + lane * 4);
  float dot0 = q0.x * k0.x + q0.y * k0.y + q0.z * k0.z + q0.w * k0.w;
  float dot1 = q1.x * k1.x + q1.y * k1.y + q1.z * k1.z + q1.w * k1.w;
  float dot2 = q2.x * k2.x + q2.y * k2.y + q2.z * k2.z + q2.w * k2.w;
  float dot3 = q3.x * k3.x + q3.y * k3.y + q3.z * k3.z + q3.w * k3.w;
#pragma unroll
  for (int off = 1; off < 16; off <<= 1) {
    dot0 += __shfl_xor(dot0, off, 64);
    dot1 += __shfl_xor(dot1, off, 64);
    dot2 += __shfl_xor(dot2, off, 64);
    dot3 += __shfl_xor(dot3, off, 64);
  }
  if ((lane & 15) == 0) {
    int h = lane >> 4;
    float* plane = logits + (size_t)h * E;
    if (v0) plane[e0] = dot0 * 0.125f;
    if (v1) plane[e1] = dot1 * 0.125f;
    if (v2) plane[e2] = dot2 * 0.125f;
    if (v3) plane[e3] = dot3 * 0.125f;
  }
}

// ---------------- attention phase 2: segment max/sum -> (m, 1/z) ----------------
__global__ void seg_softmax_kernel(const float* __restrict__ w, const int* __restrict__ row_start,
                                   float2* __restrict__ mz, int N, int E) {
  int t = blockIdx.x * blockDim.x + threadIdx.x;
  if (t >= HEADS * N) return;
  int h = t / N;
  int n = t - h * N;
  const float* plane = w + (size_t)h * E;
  int s0 = row_start[n], s1 = row_start[n + 1];
  if (s0 >= s1) return;
  float mm[4] = {-1e30f, -1e30f, -1e30f, -1e30f};
  float zz[4] = {0.f, 0.f, 0.f, 0.f};
  int i = s0;
  for (; i + 4 <= s1; i += 4) {
#pragma unroll
    for (int u = 0; u < 4; ++u) {
      float la = plane[i + u];
      float mn = fmaxf(mm[u], la);
      zz[u] = zz[u] * __expf(mm[u] - mn) + __expf(la - mn);
      mm[u] = mn;
    }
  }
  for (; i < s1; ++i) {
    float la = plane[i];
    float mn = fmaxf(mm[0], la);
    zz[0] = zz[0] * __expf(mm[0] - mn) + __expf(la - mn);
    mm[0] = mn;
  }
  float m = fmaxf(fmaxf(mm[0], mm[1]), fmaxf(mm[2], mm[3]));
  float z = zz[0] * __expf(mm[0] - m) + zz[1] * __expf(mm[1] - m) +
            zz[2] * __expf(mm[2] - m) + zz[3] * __expf(mm[3] - m);
  mz[(size_t)h * N + n] = make_float2(m, 1.f / (z + 1e-16f));
}

// ---------------- attention phase 3: fused normalize + V aggregation + ReLU -------
// block = node, wave = head; 8x unrolled gather keeps 8 V-row loads in flight.
__global__ __launch_bounds__(256) void aggregate_kernel(const float* __restrict__ qkv,
                                                        const float* __restrict__ logits,
                                                        const float2* __restrict__ mz,
                                                        const int* __restrict__ row_start,
                                                        const int* __restrict__ csr_src,
                                                        unsigned short* __restrict__ h_hi,
                                                        unsigned short* __restrict__ h_lo,
                                                        int N, int E) {
  int node = blockIdx.x;
  int wave = threadIdx.x >> 6;
  int s0 = row_start[node], s1 = row_start[node + 1];
  float h = 0.f;
  if (s1 > s0) {
    float2 p = mz[(size_t)wave * N + node];
    float m = p.x, rz = p.y;
    const float* lp = logits + (size_t)wave * E;
    const float* vbase = qkv + 512 + threadIdx.x;
    float acc = 0.f;
    int i = s0;
    for (; i + 8 <= s1; i += 8) {
      int ix[8];
      float lg[8], vv[8];
#pragma unroll
      for (int u = 0; u < 8; ++u) ix[u] = csr_src[i + u];
#pragma unroll
      for (int u = 0; u < 8; ++u) lg[u] = lp[i + u];
#pragma unroll
      for (int u = 0; u < 8; ++u) vv[u] = vbase[(size_t)ix[u] * QKVS];
#pragma unroll
      for (int u = 0; u < 8; ++u) acc = fmaf(__expf(lg[u] - m) * rz, vv[u], acc);
    }
    for (; i + 4 <= s1; i += 4) {
      int a = csr_src[i], b = csr_src[i + 1], c = csr_src[i + 2], d = csr_src[i + 3];
      float la = lp[i], lb = lp[i + 1], lc = lp[i + 2], ld = lp[i + 3];
      float va = vbase[(size_t)a * QKVS];
      float vb = vbase[(size_t)b * QKVS];
      float vc = vbase[(size_t)c * QKVS];
      float vd = vbase[(size_t)d * QKVS];
      acc = fmaf(__expf(la - m) * rz, va, acc);
      acc = fmaf(__expf(lb - m) * rz, vb, acc);
      acc = fmaf(__expf(lc - m) * rz, vc, acc);
      acc = fmaf(__expf(ld - m) * rz, vd, acc);
    }
    for (; i < s1; ++i) {
      int a = csr_src[i];
      acc = fmaf(__expf(lp[i] - m) * rz, vbase[(size_t)a * QKVS], acc);
    }
    h = fmaxf(acc, 0.f);
  }
  __bf16 hi = (__bf16)h;
  size_t idx = (size_t)node * CC + threadIdx.x;
  h_hi[idx] = __builtin_bit_cast(unsigned short, hi);
  h_lo[idx] = __builtin_bit_cast(unsigned short, (__bf16)(h - (float)hi));
}

// ---------------- pool: parallel segment-sum with atomics (batch sorted) ----------------
__global__ void pool_kernel(const unsigned short* __restrict__ h_hi,
                            const unsigned short* __restrict__ h_lo,
                            const int* __restrict__ batch,
                            float* __restrict__ gpool, int N) {
  int c = threadIdx.x;
  int n0 = blockIdx.x * 64;
  int n1 = min(n0 + 64, N);
  int cur = batch[n0];
  float acc = 0.f;
  for (int n = n0; n < n1; ++n) {
    int g = batch[n];
    if (g != cur) {
      atomicAdd(&gpool[cur * CC + c], acc);
      acc = 0.f;
      cur = g;
    }
    size_t idx = (size_t)n * CC + c;
    acc += bf2f(h_hi[idx]) + bf2f(h_lo[idx]);
  }
  atomicAdd(&gpool[cur * CC + c], acc);
}

// ---------------- MLP head ----------------
__global__ void head_kernel(const float* __restrict__ gpool, const float* __restrict__ W1,
                            const float* __restrict__ b1, const float* __restrict__ W2,
                            const float* __restrict__ b2, float* __restrict__ out) {
  __shared__ float hid[64];
  int g = blockIdx.x, t = threadIdx.x;
  float acc = b1[t];
  for (int i = 0; i < CC; ++i) acc = fmaf(gpool[g * CC + i], W1[i * 64 + t], acc);
  hid[t] = fmaxf(acc, 0.f);
  __syncthreads();
  if (t < 16) {
    float o = b2[t];
    for (int i = 0; i < 64; ++i) o = fmaf(hid[i], W2[i * 16 + t], o);
    out[g * 16 + t] = o;
  }
}

extern "C" void kernel_launch(void* const* d_in, const int* in_sizes, int n_in,
                              void* d_out, int out_size, void* d_ws, size_t ws_size,
                              hipStream_t stream) {
  const float* x  = (const float*)d_in[0];
  const int* ei   = (const int*)d_in[1];
  const int* batch = (const int*)d_in[2];
  const float* Wq = (const float*)d_in[3];
  const float* bq = (const float*)d_in[4];
  const float* Wk = (const float*)d_in[5];
  const float* bk = (const float*)d_in[6];
  const float* Wv = (const float*)d_in[7];
  const float* bv = (const float*)d_in[8];
  const float* W1 = (const float*)d_in[9];
  const float* b1 = (const float*)d_in[10];
  const float* W2 = (const float*)d_in[11];
  const float* b2 = (const float*)d_in[12];
  float* out = (float*)d_out;

  int N = in_sizes[0] / CC;
  int E = in_sizes[1] / 2;
  int L = in_sizes[3] / (CC * CC);
  const int* src = ei;
  const int* dst = ei + E;

  // workspace budget: keep total < 256 MB (R3 crashed at ~278 MB)
  size_t off = 0;
  auto alloc = [&](size_t bytes) -> void* {
    void* p = (char*)d_ws + off;
    off += (bytes + 255) & ~(size_t)255;
    return p;
  };
  float* qkv = (float*)alloc((size_t)N * QKVS * 4);                   // 153.6 MB
  unsigned short* h_hi = (unsigned short*)alloc((size_t)N * CC * 2);  // 25.6 MB
  unsigned short* h_lo = (unsigned short*)alloc((size_t)N * CC * 2);  // 25.6 MB
  unsigned short* Bth = (unsigned short*)alloc((size_t)L * QKVS * CC * 2);
  unsigned short* Btl = (unsigned short*)alloc((size_t)L * QKVS * CC * 2);
  float* biascat = (float*)alloc((size_t)L * QKVS * 4);
  int* deg = (int*)alloc((size_t)N * 4);
  int* exc = (int*)alloc((size_t)N * 4);
  int* partial = (int*)alloc(SCAN_BS * 4);
  int* row_start = (int*)alloc((size_t)(N + 1) * 4);
  int* cursor = (int*)alloc((size_t)N * 4);
  int* csr_src = (int*)alloc((size_t)E * 4);
  int* csr_dst = (int*)alloc((size_t)E * 4);
  float* wbuf = (float*)alloc((size_t)E * HEADS * 4);                 // 12.8 MB
  float2* mz = (float2*)alloc((size_t)HEADS * N * 8);                 // 1.6 MB
  float* gpool = (float*)alloc((size_t)NG * CC * 4);
  // total ~= 229 MB

  // CSR by dst
  hipMemsetAsync(deg, 0, (size_t)N * 4, stream);
  int eb = (E + 255) / 256;
  hist_kernel<<<eb, 256, 0, stream>>>(dst, deg, E);
  int nb = (N + SCAN_BS - 1) / SCAN_BS;
  scan1_kernel<<<nb, SCAN_BS, 0, stream>>>(deg, exc, partial, N);
  scan2_kernel<<<1, SCAN_BS, 0, stream>>>(partial, nb);
  scan3_kernel<<<(N + 1 + 255) / 256, 256, 0, stream>>>(exc, partial, row_start, cursor, N, E);
  scatter_kernel<<<eb, 256, 0, stream>>>(src, dst, cursor, csr_src, csr_dst, E);

  // weight prep (transpose + concat + hi/lo split)
  int wtot = L * QKVS * CC;
  wprep_kernel<<<(wtot + 255) / 256, 256, 0, stream>>>(Wq, Wk, Wv, bq, bk, bv,
                                                       Bth, Btl, biascat, L);

  // layer-0 input split
  int n4 = N * CC / 4;
  split_kernel<<<(n4 + 255) / 256, 256, 0, stream>>>(x, h_hi, h_lo, n4);

  // layers
  dim3 gemmGrid((N + 127) / 128, QKVS / 128);
  int ewb = (E + 15) / 16;
  int smb = (HEADS * N + 255) / 256;
  for (int l = 0; l < L; ++l) {
    qkv_gemm<<<gemmGrid, 256, 0, stream>>>(h_hi, h_lo,
                                           Bth + (size_t)l * QKVS * CC,
                                           Btl + (size_t)l * QKVS * CC,
                                           biascat + (size_t)l * QKVS, qkv, N);
    edge_logits_kernel<<<ewb, 256, 0, stream>>>(qkv, csr_src, csr_dst, wbuf, E);
    seg_softmax_kernel<<<smb, 256, 0, stream>>>(wbuf, row_start, mz, N, E);
    aggregate_kernel<<<N, 256, 0, stream>>>(qkv, wbuf, mz, row_start, csr_src,
                                            h_hi, h_lo, N, E);
  }

  // pool + head
  hipMemsetAsync(gpool, 0, (size_t)NG * CC * 4, stream);
  pool_kernel<<<(N + 63) / 64, 256, 0, stream>>>(h_hi, h_lo, batch, gpool, N);
  head_kernel<<<NG, 64, 0, stream>>>(gpool, W1, b1, W2, b2, out);
}